// Round 1
// baseline (229.148 us; speedup 1.0000x reference)
//
#include <hip/hip_runtime.h>
#include <hip/hip_bf16.h>

// Problem constants: x(8,64,8,64,64) fp32, w_q(32,64), w_kv(64,64)
// f = d*8+n (256), p = y*64+x (4096), p2 = y2*32+x2 (1024)

typedef __attribute__((ext_vector_type(8))) short short8;   // 8 bf16 in 4 VGPRs
typedef __attribute__((ext_vector_type(4))) float floatx4;

__device__ __forceinline__ float bf2f(short s) {
    unsigned u = ((unsigned)(unsigned short)s) << 16;
    return __builtin_bit_cast(float, u);
}
__device__ __forceinline__ short f2bf(float f) {  // RNE, finite inputs only
    unsigned u = __builtin_bit_cast(unsigned, f);
    u += 0x7fffu + ((u >> 16) & 1u);
    return (short)(u >> 16);
}

// ---------------- P1: q projection -> qraw[b][p][f] bf16 ----------------
// block = (b, y): 512 blocks x 256 threads
__global__ __launch_bounds__(256) void proj_q(const float* __restrict__ x,
                                              const float* __restrict__ wq,
                                              short* __restrict__ qraw) {
    int b = blockIdx.x >> 6, y = blockIdx.x & 63;
    __shared__ float wq_s[64 * 32];       // [c][d]
    __shared__ float xs[64 * 8 * 20];     // [c][n][20] (16 x + pad, bank-clean)
    int t = threadIdx.x;
    for (int i = t; i < 2048; i += 256) { int d = i >> 6, c = i & 63; wq_s[c * 32 + d] = wq[i]; }
    const float* xb = x + (size_t)b * 64 * 8 * 4096 + y * 64;
    int n = t & 7, d = t >> 3;
    for (int xc = 0; xc < 4; ++xc) {
        __syncthreads();
        for (int s = t; s < 2048; s += 256) {        // 8192 floats, coalesced
            int cn = s >> 2, e = s & 3;
            float4 v = *(const float4*)(xb + (size_t)cn * 4096 + xc * 16 + e * 4);
            *(float4*)(xs + cn * 20 + e * 4) = v;
        }
        __syncthreads();
        float acc[16];
#pragma unroll
        for (int i = 0; i < 16; ++i) acc[i] = 0.f;
        for (int c = 0; c < 64; ++c) {
            float wv = wq_s[c * 32 + d];
            const float* xr = xs + c * 160 + n * 20;
#pragma unroll
            for (int i = 0; i < 16; ++i) acc[i] += xr[i] * wv;
        }
        size_t base = ((size_t)(b * 4096 + y * 64 + xc * 16)) * 256 + t;
#pragma unroll
        for (int i = 0; i < 16; ++i) qraw[base + (size_t)i * 256] = f2bf(acc[i]);
    }
}

// ------------- P2: k,v projection -> kraw[b][p2][f], vraw[b][f][p2] -------------
// block = (b, y2): 256 blocks x 256 threads
__global__ __launch_bounds__(256) void proj_kv(const float* __restrict__ x,
                                               const float* __restrict__ wkv,
                                               short* __restrict__ kraw,
                                               short* __restrict__ vraw) {
    int b = blockIdx.x >> 5, y2 = blockIdx.x & 31;
    __shared__ float wkv_s[64 * 64];      // [c][e]
    __shared__ float xs[64 * 8 * 20];     // [c][n][20] (16 even-x + pad)
    int t = threadIdx.x;
    for (int i = t; i < 4096; i += 256) { int e = i >> 6, c = i & 63; wkv_s[c * 64 + e] = wkv[i]; }
    const float* xb = x + (size_t)b * 64 * 8 * 4096 + (2 * y2) * 64;
    int n = t & 7, d = t >> 3;
    float accv[32];
#pragma unroll
    for (int i = 0; i < 32; ++i) accv[i] = 0.f;
    for (int xc = 0; xc < 2; ++xc) {
        __syncthreads();
        for (int s = t; s < 4096; s += 256) {        // 512 rows x 8 float4, keep evens
            int cn = s >> 3, e = s & 7;
            float4 v = *(const float4*)(xb + (size_t)cn * 4096 + xc * 32 + e * 4);
            *(float2*)(xs + cn * 20 + e * 2) = make_float2(v.x, v.z);
        }
        __syncthreads();
        float acck[16];
#pragma unroll
        for (int i = 0; i < 16; ++i) acck[i] = 0.f;
        float* av = accv + xc * 16;
        for (int c = 0; c < 64; ++c) {
            float wk = wkv_s[c * 64 + d];
            float wv = wkv_s[c * 64 + 32 + d];
            const float* xr = xs + c * 160 + n * 20;
#pragma unroll
            for (int i = 0; i < 16; ++i) { float xv = xr[i]; acck[i] += xv * wk; av[i] += xv * wv; }
        }
        // k write: [p2][f], lanes span consecutive f -> coalesced
        size_t kbase = ((size_t)b * 1024 + y2 * 32 + xc * 16) * 256 + t;
#pragma unroll
        for (int i = 0; i < 16; ++i) kraw[kbase + (size_t)i * 256] = f2bf(acck[i]);
    }
    // v write: transposed [f][p2], 64B contiguous per lane
    short vb[32];
#pragma unroll
    for (int i = 0; i < 32; ++i) vb[i] = f2bf(accv[i]);
    size_t vbase = ((size_t)b * 256 + t) * 1024 + y2 * 32;
#pragma unroll
    for (int i = 0; i < 4; ++i) ((uint4*)(vraw + vbase))[i] = ((const uint4*)vb)[i];
}

// ---------------- Attention: fused QK^T -> softmax -> PV ----------------
// block = (b, qtile of 64 rows): 512 blocks x 256 threads (4 waves x 16 q-cols)
__global__ __launch_bounds__(256) void attn(const short* __restrict__ qraw,
                                            const short* __restrict__ kraw,
                                            const short* __restrict__ vraw,
                                            float* __restrict__ out) {
    int b = blockIdx.x >> 6, qt = blockIdx.x & 63;
    int t = threadIdx.x;
    int wv = t >> 6, lane = t & 63;
    int l16 = lane & 15, quad = lane >> 4;

    __shared__ __align__(16) short k_s[32 * 264];     // [kp][f], pad +8
    __shared__ __align__(16) short v_s[256 * 40];     // [f][kp], pad +8
    __shared__ __align__(16) short p_s[4 * 16 * 40];  // per-wave [p][kp], pad +8
    __shared__ float ks_s[32];

    // Q fragments in registers: wave owns 16 consecutive q rows (p = lane&15)
    int p_abs = qt * 64 + wv * 16 + l16;
    const short* qb = qraw + ((size_t)b * 4096 + p_abs) * 256;
    short8 qf[8];
    float sq = 0.f;
#pragma unroll
    for (int fs = 0; fs < 8; ++fs) {
        qf[fs] = *(const short8*)(qb + fs * 32 + quad * 8);
#pragma unroll
        for (int j = 0; j < 8; ++j) { float qv = bf2f(qf[fs][j]); sq += qv * qv; }
    }
    sq += __shfl_xor(sq, 16);
    sq += __shfl_xor(sq, 32);                       // full row sumsq (quads partition f)
    float qscale = 1.f / fmaxf(sqrtf(sq), 1e-12f);

    floatx4 acc[16];                                // out^T tile: 256 f x 16 p per wave
#pragma unroll
    for (int i = 0; i < 16; ++i) acc[i] = (floatx4){0.f, 0.f, 0.f, 0.f};
    float dacc = 0.f;

    for (int kc = 0; kc < 32; ++kc) {               // kp chunks of 32
        int kp0 = kc * 32;
        __syncthreads();
        {   // stage K chunk + fused kscale (norm over f per kp)
            int row = t >> 3, seg = t & 7;
            const short* src = kraw + ((size_t)b * 1024 + kp0 + row) * 256 + seg * 32;
            short* dst = k_s + row * 264 + seg * 32;
            float ss = 0.f;
#pragma unroll
            for (int j = 0; j < 4; ++j) {
                short8 vv = *(const short8*)(src + j * 8);
                *(short8*)(dst + j * 8) = vv;
#pragma unroll
                for (int q = 0; q < 8; ++q) { float kv = bf2f(vv[q]); ss += kv * kv; }
            }
            ss += __shfl_xor(ss, 1);
            ss += __shfl_xor(ss, 2);
            ss += __shfl_xor(ss, 4);
            if (seg == 0) ks_s[row] = 1.f / fmaxf(sqrtf(ss), 1e-12f);
        }
        {   // stage V chunk (vT layout already matches)
            const short* src = vraw + ((size_t)b * 256 + t) * 1024 + kp0;
            short* dst = v_s + t * 40;
#pragma unroll
            for (int j = 0; j < 4; ++j) *(short8*)(dst + j * 8) = *(const short8*)(src + j * 8);
        }
        __syncthreads();

        // MFMA1: S^T[kp][p] = K x Q^T ; scale, exp, stash P to LDS
        short* pw = p_s + wv * 16 * 40 + l16 * 40;
#pragma unroll
        for (int kt = 0; kt < 2; ++kt) {
            floatx4 c = (floatx4){0.f, 0.f, 0.f, 0.f};
#pragma unroll
            for (int fs = 0; fs < 8; ++fs) {
                short8 a = *(const short8*)(k_s + (kt * 16 + l16) * 264 + fs * 32 + quad * 8);
                c = __builtin_amdgcn_mfma_f32_16x16x32_bf16(a, qf[fs], c, 0, 0, 0);
            }
#pragma unroll
            for (int r = 0; r < 4; ++r) {
                int kpl = kt * 16 + quad * 4 + r;
                float s = c[r] * qscale * ks_s[kpl];   // |s| <= 1: exp is safe, no max needed
                float pe = __expf(s);
                dacc += pe;
                pw[kpl] = f2bf(pe);
            }
        }
        __syncthreads();

        // MFMA2: out^T[f][p] += V^T x P^T  (K=32 consumed in one mfma per f-tile)
        short8 pf = *(const short8*)(p_s + wv * 16 * 40 + l16 * 40 + quad * 8);
#pragma unroll
        for (int ft = 0; ft < 16; ++ft) {
            short8 a = *(const short8*)(v_s + (ft * 16 + l16) * 40 + quad * 8);
            acc[ft] = __builtin_amdgcn_mfma_f32_16x16x32_bf16(a, pf, acc[ft], 0, 0, 0);
        }
    }

    // denominator: lane covered its quad's kp subset; reduce across quads
    dacc += __shfl_xor(dacc, 16);
    dacc += __shfl_xor(dacc, 32);
    float inv_d = 1.f / dacc;

    // out layout [b][f][p] == reference output (b,d,n,h,w); coalesced stores
    float* ob = out + (size_t)b * 256 * 4096 + p_abs;
#pragma unroll
    for (int ft = 0; ft < 16; ++ft) {
#pragma unroll
        for (int r = 0; r < 4; ++r) {
            int f = ft * 16 + quad * 4 + r;
            ob[(size_t)f * 4096] = acc[ft][r] * inv_d;
        }
    }
}

extern "C" void kernel_launch(void* const* d_in, const int* in_sizes, int n_in,
                              void* d_out, int out_size, void* d_ws, size_t ws_size,
                              hipStream_t stream) {
    (void)in_sizes; (void)n_in; (void)out_size; (void)ws_size;
    const float* x   = (const float*)d_in[0];
    const float* wq  = (const float*)d_in[1];
    const float* wkv = (const float*)d_in[2];
    float* out = (float*)d_out;

    char* ws = (char*)d_ws;
    short* qraw = (short*)ws;                                  // 8*4096*256*2 = 16 MiB
    short* kraw = (short*)(ws + 16777216);                     // 8*1024*256*2 = 4 MiB
    short* vraw = (short*)(ws + 16777216 + 4194304);           // 8*256*1024*2 = 4 MiB

    proj_q <<<512, 256, 0, stream>>>(x, wq, qraw);
    proj_kv<<<256, 256, 0, stream>>>(x, wkv, kraw, vraw);
    attn   <<<512, 256, 0, stream>>>(qraw, kraw, vraw, out);
}

// Round 3
// 207.743 us; speedup vs baseline: 1.1030x; 1.1030x over previous
//
#include <hip/hip_runtime.h>

// x(8,64,8,64,64) fp32, w_q(32,64), w_kv(64,64)
// f = d*8+n (256), p = y*64+xi (4096), p2 = y2*32+x2 (1024)

typedef __attribute__((ext_vector_type(8))) short short8;
typedef __attribute__((ext_vector_type(4))) float floatx4;

__device__ __forceinline__ short f2bf(float f) {  // RNE, finite only
    unsigned u = __builtin_bit_cast(unsigned, f);
    u += 0x7fffu + ((u >> 16) & 1u);
    return (short)(u >> 16);
}
__device__ __forceinline__ unsigned pack2bf(float a, float b) {
    return (unsigned)(unsigned short)f2bf(a) | ((unsigned)(unsigned short)f2bf(b) << 16);
}

// ---------------- Fused projection: q (normalized), k (normalized), v ----------------
// grid 512 = (b, y); thread t: n=t>>5, dg=(t>>3)&3 (d=dg*8+j), xc=t&7 (xi=xc*4+i within half)
__global__ __launch_bounds__(256) void proj(const float* __restrict__ x,
                                            const float* __restrict__ wq,
                                            const float* __restrict__ wkv,
                                            short* __restrict__ qraw,
                                            short* __restrict__ kraw,
                                            short* __restrict__ vraw) {
    int b = blockIdx.x >> 6, y = blockIdx.x & 63;
    int t = threadIdx.x;
    int n = t >> 5, dg = (t >> 3) & 3, xc = t & 7;
    bool kv = (y & 1) == 0;
    int y2 = y >> 1;

    __shared__ __align__(16) float wq_s[64 * 32];   // [c][d]
    __shared__ __align__(16) float wkv_s[64 * 64];  // [c][e]
    __shared__ __align__(16) float xs[128 * 36];    // [c16*n8][32xi + pad]; overlaid by q_lds
    __shared__ __align__(16) short k_lds[16 * 264];
    __shared__ __align__(16) short v_lds[256 * 16]; // [f][xi2]
    __shared__ float red[32 * 33];
    __shared__ float nrm[32];
    short* q_lds = (short*)xs;                      // 16896 B <= 18432 B

    for (int i = t; i < 2048; i += 256) { int d = i >> 6, c = i & 63; wq_s[c * 32 + d] = wq[i]; }
    for (int i = t; i < 4096; i += 256) { int e = i >> 6, c = i & 63; wkv_s[c * 64 + e] = wkv[i]; }
    // x batch stride = c*n*h*w = 64*8*64*64 = 2097152  (R2 bug: was 262144)
    const float* xb = x + (size_t)b * 2097152 + y * 64;

    for (int xh = 0; xh < 2; ++xh) {
        float qa[8][4], ka[8][2], va[8][2];
#pragma unroll
        for (int j = 0; j < 8; ++j) {
            qa[j][0] = qa[j][1] = qa[j][2] = qa[j][3] = 0.f;
            ka[j][0] = ka[j][1] = 0.f; va[j][0] = va[j][1] = 0.f;
        }
        for (int cc = 0; cc < 4; ++cc) {
            __syncthreads();
#pragma unroll
            for (int it = 0; it < 4; ++it) {
                int i = it * 256 + t, cn = i >> 3, e = i & 7;
                float4 v = *(const float4*)(xb + (size_t)(cc * 16 + (cn >> 3)) * 32768 + (cn & 7) * 4096 + xh * 32 + e * 4);
                *(float4*)(xs + cn * 36 + e * 4) = v;
            }
            __syncthreads();
            for (int c = 0; c < 16; ++c) {
                float4 xv = *(const float4*)(xs + (c * 8 + n) * 36 + xc * 4);
                float xw[4] = {xv.x, xv.y, xv.z, xv.w};
                int cg = cc * 16 + c;
                float4 wqa = *(const float4*)(wq_s + cg * 32 + dg * 8);
                float4 wqb = *(const float4*)(wq_s + cg * 32 + dg * 8 + 4);
                float wj[8] = {wqa.x, wqa.y, wqa.z, wqa.w, wqb.x, wqb.y, wqb.z, wqb.w};
#pragma unroll
                for (int j = 0; j < 8; ++j)
#pragma unroll
                    for (int i2 = 0; i2 < 4; ++i2) qa[j][i2] += wj[j] * xw[i2];
                if (kv) {
                    float4 wka = *(const float4*)(wkv_s + cg * 64 + dg * 8);
                    float4 wkb = *(const float4*)(wkv_s + cg * 64 + dg * 8 + 4);
                    float4 wva = *(const float4*)(wkv_s + cg * 64 + 32 + dg * 8);
                    float4 wvb = *(const float4*)(wkv_s + cg * 64 + 32 + dg * 8 + 4);
                    float wk[8] = {wka.x, wka.y, wka.z, wka.w, wkb.x, wkb.y, wkb.z, wkb.w};
                    float wv2[8] = {wva.x, wva.y, wva.z, wva.w, wvb.x, wvb.y, wvb.z, wvb.w};
#pragma unroll
                    for (int j = 0; j < 8; ++j) {
                        ka[j][0] += wk[j] * xw[0]; ka[j][1] += wk[j] * xw[2];
                        va[j][0] += wv2[j] * xw[0]; va[j][1] += wv2[j] * xw[2];
                    }
                }
            }
        }
        // ---- q: row-l2norm over f, write bf16 via LDS, coalesced flush ----
        __syncthreads();   // all reads of xs done (q_lds overlays xs)
#pragma unroll
        for (int i2 = 0; i2 < 4; ++i2) {
            float s = 0.f;
#pragma unroll
            for (int j = 0; j < 8; ++j) s += qa[j][i2] * qa[j][i2];
            red[(xc * 4 + i2) * 33 + n * 4 + dg] = s;
        }
        __syncthreads();
        if (t < 32) {
            float s = 0.f;
            for (int k = 0; k < 32; ++k) s += red[t * 33 + k];
            nrm[t] = 1.f / fmaxf(sqrtf(s), 1e-12f);
        }
        __syncthreads();
#pragma unroll
        for (int i2 = 0; i2 < 4; ++i2) {
            float sc = nrm[xc * 4 + i2];
#pragma unroll
            for (int j = 0; j < 8; ++j)
                q_lds[(xc * 4 + i2) * 264 + (dg * 8 + j) * 8 + n] = f2bf(qa[j][i2] * sc);
        }
        __syncthreads();
        {
            size_t qg = ((size_t)b * 4096 + y * 64 + xh * 32) * 256;
#pragma unroll
            for (int it = 0; it < 4; ++it) {
                int r = it * 8 + (t >> 5), sg = t & 31;
                *(uint4*)(qraw + qg + (size_t)r * 256 + sg * 8) = *(const uint4*)(q_lds + r * 264 + sg * 8);
            }
        }
        // ---- k (col-l2norm over f) and v ----
        if (kv) {
            __syncthreads();
#pragma unroll
            for (int ii = 0; ii < 2; ++ii) {
                float s = 0.f;
#pragma unroll
                for (int j = 0; j < 8; ++j) s += ka[j][ii] * ka[j][ii];
                red[(xc * 2 + ii) * 33 + n * 4 + dg] = s;
            }
            __syncthreads();
            if (t < 16) {
                float s = 0.f;
                for (int k = 0; k < 32; ++k) s += red[t * 33 + k];
                nrm[t] = 1.f / fmaxf(sqrtf(s), 1e-12f);
            }
            __syncthreads();
#pragma unroll
            for (int ii = 0; ii < 2; ++ii) {
                float sc = nrm[xc * 2 + ii];
#pragma unroll
                for (int j = 0; j < 8; ++j) {
                    int f = (dg * 8 + j) * 8 + n;
                    k_lds[(xc * 2 + ii) * 264 + f] = f2bf(ka[j][ii] * sc);
                    v_lds[f * 16 + xc * 2 + ii] = f2bf(va[j][ii]);
                }
            }
            __syncthreads();
            size_t kg = ((size_t)b * 1024 + y2 * 32 + xh * 16) * 256;
#pragma unroll
            for (int it = 0; it < 2; ++it) {
                int r = it * 8 + (t >> 5), sg = t & 31;
                *(uint4*)(kraw + kg + (size_t)r * 256 + sg * 8) = *(const uint4*)(k_lds + r * 264 + sg * 8);
            }
            size_t vg = (size_t)b * 262144 + (size_t)y2 * 32 + xh * 16;
#pragma unroll
            for (int it = 0; it < 2; ++it) {
                int idx = it * 256 + t, f = idx >> 1, hh = idx & 1;
                *(uint4*)(vraw + vg + (size_t)f * 1024 + hh * 8) = *(const uint4*)(v_lds + f * 16 + hh * 8);
            }
        }
    }
}

// ---------------- attn: qtile=128, 4 waves; phase1 p-owned, phase2 f-partitioned ----------------
// grid 256 = (b, qt of 128 rows), 256 threads
__global__ __launch_bounds__(256, 1) void attn(const short* __restrict__ qraw,
                                               const short* __restrict__ kraw,
                                               const short* __restrict__ vraw,
                                               float* __restrict__ out) {
    int b = blockIdx.x >> 5, qt = blockIdx.x & 31;
    int t = threadIdx.x, wv = t >> 6, lane = t & 63, l16 = lane & 15, quad = lane >> 4;

    __shared__ __align__(16) short k_s[32 * 264];  // [kp][f]+pad
    __shared__ __align__(16) short v_s[256 * 40];  // [f][kp]+pad
    __shared__ __align__(16) short p_s[128 * 40];  // [p][kp]+pad
    __shared__ float dsum[128];

    // Q fragments (prenormalized): wave owns p = qt*128 + wv*32 + pt*16 + l16
    short8 qf[2][8];
    const short* qb = qraw + ((size_t)b * 4096 + qt * 128 + wv * 32) * 256;
#pragma unroll
    for (int pt = 0; pt < 2; ++pt)
#pragma unroll
        for (int fs = 0; fs < 8; ++fs)
            qf[pt][fs] = *(const short8*)(qb + (pt * 16 + l16) * 256 + fs * 32 + quad * 8);

    floatx4 acc[8][4];  // [p-tile of 16][f-tile of 16 within wave's 64-f slice]
#pragma unroll
    for (int i = 0; i < 8; ++i)
#pragma unroll
        for (int j = 0; j < 4; ++j) acc[i][j] = (floatx4){0.f, 0.f, 0.f, 0.f};
    float dacc0 = 0.f, dacc1 = 0.f;

    int krow = t >> 3, kseg = t & 7;
    const short* kbase = kraw + ((size_t)b * 1024 + krow) * 256 + kseg * 32;
    const short* vbase = vraw + ((size_t)b * 256 + t) * 1024;

    short8 kst[4], vst[4];
#pragma unroll
    for (int j = 0; j < 4; ++j) {
        kst[j] = *(const short8*)(kbase + j * 8);
        vst[j] = *(const short8*)(vbase + j * 8);
    }
#pragma unroll
    for (int j = 0; j < 4; ++j) {
        *(short8*)(k_s + krow * 264 + kseg * 32 + j * 8) = kst[j];
        *(short8*)(v_s + t * 40 + j * 8) = vst[j];
    }
    __syncthreads();

    for (int kc = 0; kc < 32; ++kc) {
        if (kc < 31) {  // prefetch next chunk into registers
            int kp0n = (kc + 1) * 32;
#pragma unroll
            for (int j = 0; j < 4; ++j) {
                kst[j] = *(const short8*)(kbase + (size_t)kp0n * 256 + j * 8);
                vst[j] = *(const short8*)(vbase + kp0n + j * 8);
            }
        }
        // phase 1: S^T[kp][p] for wave's 32 p; A-frag reused across both p-tiles
        floatx4 cc0[2] = {(floatx4){0.f,0.f,0.f,0.f}, (floatx4){0.f,0.f,0.f,0.f}};
        floatx4 cc1[2] = {(floatx4){0.f,0.f,0.f,0.f}, (floatx4){0.f,0.f,0.f,0.f}};
#pragma unroll
        for (int kt = 0; kt < 2; ++kt) {
#pragma unroll
            for (int fs = 0; fs < 8; ++fs) {
                short8 a = *(const short8*)(k_s + (kt * 16 + l16) * 264 + fs * 32 + quad * 8);
                cc0[kt] = __builtin_amdgcn_mfma_f32_16x16x32_bf16(a, qf[0][fs], cc0[kt], 0, 0, 0);
                cc1[kt] = __builtin_amdgcn_mfma_f32_16x16x32_bf16(a, qf[1][fs], cc1[kt], 0, 0, 0);
            }
        }
        // |s|<=1: plain exp, no max-subtraction; stash P (bf16) and partial denominators
#pragma unroll
        for (int kt = 0; kt < 2; ++kt) {
#pragma unroll
            for (int pr = 0; pr < 2; ++pr) {
                float e0 = __expf(cc0[kt][2 * pr]), e1 = __expf(cc0[kt][2 * pr + 1]);
                dacc0 += e0 + e1;
                *(unsigned*)(p_s + (wv * 32 + l16) * 40 + kt * 16 + quad * 4 + 2 * pr) = pack2bf(e0, e1);
                float e2 = __expf(cc1[kt][2 * pr]), e3 = __expf(cc1[kt][2 * pr + 1]);
                dacc1 += e2 + e3;
                *(unsigned*)(p_s + (wv * 32 + 16 + l16) * 40 + kt * 16 + quad * 4 + 2 * pr) = pack2bf(e2, e3);
            }
        }
        __syncthreads();
        // phase 2: out^T[f][p] += V^T x P^T ; wave owns f slice [wv*64, wv*64+64), all 128 p
        short8 av[4];
#pragma unroll
        for (int fl = 0; fl < 4; ++fl)
            av[fl] = *(const short8*)(v_s + (wv * 64 + fl * 16 + l16) * 40 + quad * 8);
#pragma unroll
        for (int p2 = 0; p2 < 8; ++p2) {
            short8 bq = *(const short8*)(p_s + (p2 * 16 + l16) * 40 + quad * 8);
#pragma unroll
            for (int fl = 0; fl < 4; ++fl)
                acc[p2][fl] = __builtin_amdgcn_mfma_f32_16x16x32_bf16(av[fl], bq, acc[p2][fl], 0, 0, 0);
        }
        __syncthreads();
        if (kc < 31) {  // commit prefetched tiles
#pragma unroll
            for (int j = 0; j < 4; ++j) {
                *(short8*)(k_s + krow * 264 + kseg * 32 + j * 8) = kst[j];
                *(short8*)(v_s + t * 40 + j * 8) = vst[j];
            }
            __syncthreads();
        }
    }
    // denominators: reduce quads, share across waves
    dacc0 += __shfl_xor(dacc0, 16); dacc0 += __shfl_xor(dacc0, 32);
    dacc1 += __shfl_xor(dacc1, 16); dacc1 += __shfl_xor(dacc1, 32);
    if (quad == 0) {
        dsum[wv * 32 + l16] = dacc0;
        dsum[wv * 32 + 16 + l16] = dacc1;
    }
    __syncthreads();
    float* ob = out + (size_t)b * 1048576 + qt * 128;
#pragma unroll
    for (int p2 = 0; p2 < 8; ++p2) {
        float inv = 1.f / dsum[p2 * 16 + l16];
#pragma unroll
        for (int fl = 0; fl < 4; ++fl) {
            int f0 = wv * 64 + fl * 16 + quad * 4;
#pragma unroll
            for (int r = 0; r < 4; ++r)
                ob[(size_t)(f0 + r) * 4096 + p2 * 16 + l16] = acc[p2][fl][r] * inv;
        }
    }
}

extern "C" void kernel_launch(void* const* d_in, const int* in_sizes, int n_in,
                              void* d_out, int out_size, void* d_ws, size_t ws_size,
                              hipStream_t stream) {
    (void)in_sizes; (void)n_in; (void)out_size; (void)ws_size;
    const float* x   = (const float*)d_in[0];
    const float* wqp = (const float*)d_in[1];
    const float* wkv = (const float*)d_in[2];
    float* out = (float*)d_out;

    char* ws = (char*)d_ws;
    short* qraw = (short*)ws;                          // 16 MiB, [b][p][f] normalized bf16
    short* kraw = (short*)(ws + 16777216);             // 4 MiB,  [b][p2][f] normalized bf16
    short* vraw = (short*)(ws + 16777216 + 4194304);   // 4 MiB,  [b][f][p2] bf16

    proj<<<512, 256, 0, stream>>>(x, wqp, wkv, qraw, kraw, vraw);
    attn<<<256, 256, 0, stream>>>(qraw, kraw, vraw, out);
}

// Round 4
// 194.548 us; speedup vs baseline: 1.1778x; 1.0678x over previous
//
#include <hip/hip_runtime.h>

// x(8,64,8,64,64) fp32, w_q(32,64), w_kv(64,64)
// f = d*8+n (256), p = y*64+xi (4096), p2 = y2*32+x2 (1024)

typedef __attribute__((ext_vector_type(8))) short short8;
typedef __attribute__((ext_vector_type(4))) float floatx4;
typedef __attribute__((ext_vector_type(2))) unsigned uintx2;

__device__ __forceinline__ short f2bf(float f) {  // RNE, finite only
    unsigned u = __builtin_bit_cast(unsigned, f);
    u += 0x7fffu + ((u >> 16) & 1u);
    return (short)(u >> 16);
}
__device__ __forceinline__ unsigned pack2bf(float a, float b) {
    return (unsigned)(unsigned short)f2bf(a) | ((unsigned)(unsigned short)f2bf(b) << 16);
}

// ---------------- Fused projection: q (normalized), k (normalized), v ----------------
// grid 512 = (b, y); thread t: n=t>>5, dg=(t>>3)&3 (d=dg*8+j), xc=t&7 (xi=xc*4+i within half)
__global__ __launch_bounds__(256) void proj(const float* __restrict__ x,
                                            const float* __restrict__ wq,
                                            const float* __restrict__ wkv,
                                            short* __restrict__ qraw,
                                            short* __restrict__ kraw,
                                            short* __restrict__ vraw) {
    int b = blockIdx.x >> 6, y = blockIdx.x & 63;
    int t = threadIdx.x;
    int n = t >> 5, dg = (t >> 3) & 3, xc = t & 7;
    bool kv = (y & 1) == 0;
    int y2 = y >> 1;

    __shared__ __align__(16) float wq_s[64 * 32];   // [c][d]
    __shared__ __align__(16) float wkv_s[64 * 64];  // [c][e]
    __shared__ __align__(16) float xs[128 * 36];    // [c16*n8][32xi + pad]; overlaid by q_lds
    __shared__ __align__(16) short k_lds[16 * 264];
    __shared__ __align__(16) short v_lds[256 * 16]; // [f][xi2]
    __shared__ float red[32 * 33];
    __shared__ float nrm[32];
    short* q_lds = (short*)xs;                      // 16896 B <= 18432 B

    for (int i = t; i < 2048; i += 256) { int d = i >> 6, c = i & 63; wq_s[c * 32 + d] = wq[i]; }
    for (int i = t; i < 4096; i += 256) { int e = i >> 6, c = i & 63; wkv_s[c * 64 + e] = wkv[i]; }
    const float* xb = x + (size_t)b * 2097152 + y * 64;   // batch stride c*n*h*w

    for (int xh = 0; xh < 2; ++xh) {
        float qa[8][4], ka[8][2], va[8][2];
#pragma unroll
        for (int j = 0; j < 8; ++j) {
            qa[j][0] = qa[j][1] = qa[j][2] = qa[j][3] = 0.f;
            ka[j][0] = ka[j][1] = 0.f; va[j][0] = va[j][1] = 0.f;
        }
        for (int cc = 0; cc < 4; ++cc) {
            __syncthreads();
#pragma unroll
            for (int it = 0; it < 4; ++it) {
                int i = it * 256 + t, cn = i >> 3, e = i & 7;
                float4 v = *(const float4*)(xb + (size_t)(cc * 16 + (cn >> 3)) * 32768 + (cn & 7) * 4096 + xh * 32 + e * 4);
                *(float4*)(xs + cn * 36 + e * 4) = v;
            }
            __syncthreads();
            for (int c = 0; c < 16; ++c) {
                float4 xv = *(const float4*)(xs + (c * 8 + n) * 36 + xc * 4);
                float xw[4] = {xv.x, xv.y, xv.z, xv.w};
                int cg = cc * 16 + c;
                float4 wqa = *(const float4*)(wq_s + cg * 32 + dg * 8);
                float4 wqb = *(const float4*)(wq_s + cg * 32 + dg * 8 + 4);
                float wj[8] = {wqa.x, wqa.y, wqa.z, wqa.w, wqb.x, wqb.y, wqb.z, wqb.w};
#pragma unroll
                for (int j = 0; j < 8; ++j)
#pragma unroll
                    for (int i2 = 0; i2 < 4; ++i2) qa[j][i2] += wj[j] * xw[i2];
                if (kv) {
                    float4 wka = *(const float4*)(wkv_s + cg * 64 + dg * 8);
                    float4 wkb = *(const float4*)(wkv_s + cg * 64 + dg * 8 + 4);
                    float4 wva = *(const float4*)(wkv_s + cg * 64 + 32 + dg * 8);
                    float4 wvb = *(const float4*)(wkv_s + cg * 64 + 32 + dg * 8 + 4);
                    float wk[8] = {wka.x, wka.y, wka.z, wka.w, wkb.x, wkb.y, wkb.z, wkb.w};
                    float wv2[8] = {wva.x, wva.y, wva.z, wva.w, wvb.x, wvb.y, wvb.z, wvb.w};
#pragma unroll
                    for (int j = 0; j < 8; ++j) {
                        ka[j][0] += wk[j] * xw[0]; ka[j][1] += wk[j] * xw[2];
                        va[j][0] += wv2[j] * xw[0]; va[j][1] += wv2[j] * xw[2];
                    }
                }
            }
        }
        // ---- q: row-l2norm over f, write bf16 via LDS, coalesced flush ----
        __syncthreads();   // all reads of xs done (q_lds overlays xs)
#pragma unroll
        for (int i2 = 0; i2 < 4; ++i2) {
            float s = 0.f;
#pragma unroll
            for (int j = 0; j < 8; ++j) s += qa[j][i2] * qa[j][i2];
            red[(xc * 4 + i2) * 33 + n * 4 + dg] = s;
        }
        __syncthreads();
        if (t < 32) {
            float s = 0.f;
            for (int k = 0; k < 32; ++k) s += red[t * 33 + k];
            nrm[t] = 1.f / fmaxf(sqrtf(s), 1e-12f);
        }
        __syncthreads();
#pragma unroll
        for (int i2 = 0; i2 < 4; ++i2) {
            float sc = nrm[xc * 4 + i2];
#pragma unroll
            for (int j = 0; j < 8; ++j)
                q_lds[(xc * 4 + i2) * 264 + (dg * 8 + j) * 8 + n] = f2bf(qa[j][i2] * sc);
        }
        __syncthreads();
        {
            size_t qg = ((size_t)b * 4096 + y * 64 + xh * 32) * 256;
#pragma unroll
            for (int it = 0; it < 4; ++it) {
                int r = it * 8 + (t >> 5), sg = t & 31;
                *(uint4*)(qraw + qg + (size_t)r * 256 + sg * 8) = *(const uint4*)(q_lds + r * 264 + sg * 8);
            }
        }
        // ---- k (col-l2norm over f) and v ----
        if (kv) {
            __syncthreads();
#pragma unroll
            for (int ii = 0; ii < 2; ++ii) {
                float s = 0.f;
#pragma unroll
                for (int j = 0; j < 8; ++j) s += ka[j][ii] * ka[j][ii];
                red[(xc * 2 + ii) * 33 + n * 4 + dg] = s;
            }
            __syncthreads();
            if (t < 16) {
                float s = 0.f;
                for (int k = 0; k < 32; ++k) s += red[t * 33 + k];
                nrm[t] = 1.f / fmaxf(sqrtf(s), 1e-12f);
            }
            __syncthreads();
#pragma unroll
            for (int ii = 0; ii < 2; ++ii) {
                float sc = nrm[xc * 2 + ii];
#pragma unroll
                for (int j = 0; j < 8; ++j) {
                    int f = (dg * 8 + j) * 8 + n;
                    k_lds[(xc * 2 + ii) * 264 + f] = f2bf(ka[j][ii] * sc);
                    v_lds[f * 16 + xc * 2 + ii] = f2bf(va[j][ii]);
                }
            }
            __syncthreads();
            size_t kg = ((size_t)b * 1024 + y2 * 32 + xh * 16) * 256;
#pragma unroll
            for (int it = 0; it < 2; ++it) {
                int r = it * 8 + (t >> 5), sg = t & 31;
                *(uint4*)(kraw + kg + (size_t)r * 256 + sg * 8) = *(const uint4*)(k_lds + r * 264 + sg * 8);
            }
            size_t vg = (size_t)b * 262144 + (size_t)y2 * 32 + xh * 16;
#pragma unroll
            for (int it = 0; it < 2; ++it) {
                int idx = it * 256 + t, f = idx >> 1, hh = idx & 1;
                *(uint4*)(vraw + vg + (size_t)f * 1024 + hh * 8) = *(const uint4*)(v_lds + f * 16 + hh * 8);
            }
        }
    }
}

// ---------------- attn: qtile=128, 4 waves; double-buffered LDS, 2 barriers/kc ----------------
// grid 256 = (b, qt of 128 rows), 256 threads
__global__ __launch_bounds__(256, 1) void attn(const short* __restrict__ qraw,
                                               const short* __restrict__ kraw,
                                               const short* __restrict__ vraw,
                                               float* __restrict__ out) {
    int b = blockIdx.x >> 5, qt = blockIdx.x & 31;
    int t = threadIdx.x, wv = t >> 6, lane = t & 63, l16 = lane & 15, quad = lane >> 4;

    __shared__ __align__(16) short k_s[2][32 * 264];  // [kp][f]+pad, 2x16.9KB
    __shared__ __align__(16) short v_s[2][256 * 40];  // [f][kp]+pad, 2x20.5KB
    __shared__ __align__(16) short p_s[2][128 * 40];  // [p][kp]+pad, 2x10.25KB
    __shared__ float dsum[128];

    // Q fragments (prenormalized): wave owns p = qt*128 + wv*32 + pt*16 + l16
    short8 qf[2][8];
    const short* qb = qraw + ((size_t)b * 4096 + qt * 128 + wv * 32) * 256;
#pragma unroll
    for (int pt = 0; pt < 2; ++pt)
#pragma unroll
        for (int fs = 0; fs < 8; ++fs)
            qf[pt][fs] = *(const short8*)(qb + (pt * 16 + l16) * 256 + fs * 32 + quad * 8);

    floatx4 acc[8][4];  // [p-tile of 16][f-tile of 16 within wave's 64-f slice]
#pragma unroll
    for (int i = 0; i < 8; ++i)
#pragma unroll
        for (int j = 0; j < 4; ++j) acc[i][j] = (floatx4){0.f, 0.f, 0.f, 0.f};
    float dacc0 = 0.f, dacc1 = 0.f;

    int krow = t >> 3, kseg = t & 7;
    const short* kbase = kraw + ((size_t)b * 1024 + krow) * 256 + kseg * 32;
    const short* vbase = vraw + ((size_t)b * 256 + t) * 1024;

    short8 kst[4], vst[4];
    // stage chunk 0 into buffer 0
#pragma unroll
    for (int j = 0; j < 4; ++j) {
        kst[j] = *(const short8*)(kbase + j * 8);
        vst[j] = *(const short8*)(vbase + j * 8);
    }
#pragma unroll
    for (int j = 0; j < 4; ++j) {
        *(short8*)(k_s[0] + krow * 264 + kseg * 32 + j * 8) = kst[j];
        *(short8*)(v_s[0] + t * 40 + j * 8) = vst[j];
    }
    // prefetch chunk 1 into regs
#pragma unroll
    for (int j = 0; j < 4; ++j) {
        kst[j] = *(const short8*)(kbase + (size_t)32 * 256 + j * 8);
        vst[j] = *(const short8*)(vbase + 32 + j * 8);
    }
    __syncthreads();

    for (int kc = 0; kc < 32; ++kc) {
        int cur = kc & 1, nxt = cur ^ 1;
        // phase 1: S^T[kp][p] for wave's 32 p; A-frag reused across both p-tiles
        floatx4 cc0[2] = {(floatx4){0.f,0.f,0.f,0.f}, (floatx4){0.f,0.f,0.f,0.f}};
        floatx4 cc1[2] = {(floatx4){0.f,0.f,0.f,0.f}, (floatx4){0.f,0.f,0.f,0.f}};
#pragma unroll
        for (int kt = 0; kt < 2; ++kt) {
#pragma unroll
            for (int fs = 0; fs < 8; ++fs) {
                short8 a = *(const short8*)(k_s[cur] + (kt * 16 + l16) * 264 + fs * 32 + quad * 8);
                cc0[kt] = __builtin_amdgcn_mfma_f32_16x16x32_bf16(a, qf[0][fs], cc0[kt], 0, 0, 0);
                cc1[kt] = __builtin_amdgcn_mfma_f32_16x16x32_bf16(a, qf[1][fs], cc1[kt], 0, 0, 0);
            }
        }
        // |s|<=1: plain exp; stash P rows as one b64 per (kt,qset): cols kt*16+quad*4..+3
#pragma unroll
        for (int kt = 0; kt < 2; ++kt) {
            float e0 = __expf(cc0[kt][0]), e1 = __expf(cc0[kt][1]);
            float e2 = __expf(cc0[kt][2]), e3 = __expf(cc0[kt][3]);
            dacc0 += (e0 + e1) + (e2 + e3);
            uintx2 w0; w0[0] = pack2bf(e0, e1); w0[1] = pack2bf(e2, e3);
            *(uintx2*)(p_s[cur] + (wv * 32 + l16) * 40 + kt * 16 + quad * 4) = w0;
            float f0 = __expf(cc1[kt][0]), f1 = __expf(cc1[kt][1]);
            float f2 = __expf(cc1[kt][2]), f3 = __expf(cc1[kt][3]);
            dacc1 += (f0 + f1) + (f2 + f3);
            uintx2 w1; w1[0] = pack2bf(f0, f1); w1[1] = pack2bf(f2, f3);
            *(uintx2*)(p_s[cur] + (wv * 32 + 16 + l16) * 40 + kt * 16 + quad * 4) = w1;
        }
        __syncthreads();   // B1: P[cur] ready for cross-wave reads

        // commit prefetched chunk kc+1 into [nxt] (readers of [nxt] start only after B2)
        if (kc < 31) {
#pragma unroll
            for (int j = 0; j < 4; ++j) {
                *(short8*)(k_s[nxt] + krow * 264 + kseg * 32 + j * 8) = kst[j];
                *(short8*)(v_s[nxt] + t * 40 + j * 8) = vst[j];
            }
        }
        // phase 2: out^T[f][p] += V^T x P^T ; wave owns f slice [wv*64, +64), all 128 p
        short8 av[4];
#pragma unroll
        for (int fl = 0; fl < 4; ++fl)
            av[fl] = *(const short8*)(v_s[cur] + (wv * 64 + fl * 16 + l16) * 40 + quad * 8);
#pragma unroll
        for (int p2 = 0; p2 < 8; ++p2) {
            short8 bq = *(const short8*)(p_s[cur] + (p2 * 16 + l16) * 40 + quad * 8);
#pragma unroll
            for (int fl = 0; fl < 4; ++fl)
                acc[p2][fl] = __builtin_amdgcn_mfma_f32_16x16x32_bf16(av[fl], bq, acc[p2][fl], 0, 0, 0);
        }
        // prefetch chunk kc+2 into regs (global; independent of LDS)
        if (kc < 30) {
            int kp0n = (kc + 2) * 32;
#pragma unroll
            for (int j = 0; j < 4; ++j) {
                kst[j] = *(const short8*)(kbase + (size_t)kp0n * 256 + j * 8);
                vst[j] = *(const short8*)(vbase + kp0n + j * 8);
            }
        }
        __syncthreads();   // B2: [cur] reads done; commit of [nxt] visible for next phase1
    }
    // denominators: reduce quads, share across waves
    dacc0 += __shfl_xor(dacc0, 16); dacc0 += __shfl_xor(dacc0, 32);
    dacc1 += __shfl_xor(dacc1, 16); dacc1 += __shfl_xor(dacc1, 32);
    if (quad == 0) {
        dsum[wv * 32 + l16] = dacc0;
        dsum[wv * 32 + 16 + l16] = dacc1;
    }
    __syncthreads();
    float* ob = out + (size_t)b * 1048576 + qt * 128;
#pragma unroll
    for (int p2 = 0; p2 < 8; ++p2) {
        float inv = 1.f / dsum[p2 * 16 + l16];
#pragma unroll
        for (int fl = 0; fl < 4; ++fl) {
            int f0 = wv * 64 + fl * 16 + quad * 4;
#pragma unroll
            for (int r = 0; r < 4; ++r)
                ob[(size_t)(f0 + r) * 4096 + p2 * 16 + l16] = acc[p2][fl][r] * inv;
        }
    }
}

extern "C" void kernel_launch(void* const* d_in, const int* in_sizes, int n_in,
                              void* d_out, int out_size, void* d_ws, size_t ws_size,
                              hipStream_t stream) {
    (void)in_sizes; (void)n_in; (void)out_size; (void)ws_size;
    const float* x   = (const float*)d_in[0];
    const float* wqp = (const float*)d_in[1];
    const float* wkv = (const float*)d_in[2];
    float* out = (float*)d_out;

    char* ws = (char*)d_ws;
    short* qraw = (short*)ws;                          // 16 MiB, [b][p][f] normalized bf16
    short* kraw = (short*)(ws + 16777216);             // 4 MiB,  [b][p2][f] normalized bf16
    short* vraw = (short*)(ws + 16777216 + 4194304);   // 4 MiB,  [b][f][p2] bf16

    proj<<<512, 256, 0, stream>>>(x, wqp, wkv, qraw, kraw, vraw);
    attn<<<256, 256, 0, stream>>>(qraw, kraw, vraw, out);
}